// Round 6
// baseline (300.137 us; speedup 1.0000x reference)
//
#include <hip/hip_runtime.h>
#include <stdint.h>
#include <stddef.h>

#define NLVL 16
#define NLG 8                 // levels per enc kernel
#define TABROWS 16384
#define BLK 1024
#define NBLK 1024             // 1048576 / 1024 points, 1 point/thread
#define LVLBYTES (TABROWS * 8)   // 131072 B: one full fp32 level slice (16384 x 2 f32)

constexpr int RES_[NLVL] = {16,20,25,32,40,50,64,80,101,128,161,203,256,322,406,512};

typedef __attribute__((address_space(1))) void gv_t;
typedef __attribute__((address_space(3))) void lv_t;

// ---- enc: 8 levels [LBASE, LBASE+8), 1 point/thread.
//      NO WORKSPACE: gathers fp32 directly from the original emb tables.
//      The 512 MiB workspace re-poison fill (83 us, ~31% of round-0's timed
//      window) only exists because we used d_ws; dropping the fp16 conversion
//      removes cvt_tab AND (hypothesis) the poison fill. One fp32 level slice
//      is exactly 128 KiB -> single LDS buffer (no room to double-buffer in
//      160 KiB). Staging always copies the full slice: padding rows of dense
//      levels are staged but never indexed (ids < n_enc), so no byte-count
//      table / guard branch. Exposed per-phase staging costs ~+13 us/enc vs
//      round 0's dbuf; the removed fill + cvt is -88 us. VGPR demand ~56
//      (= round 0), safely under the hard 64-reg wall at BLK=1024
//      (rounds 1/3/4/5: exceeding it => clamp + ~250 MB scratch spill). ----
template<int LBASE>
__global__ __launch_bounds__(BLK) void enc(const float* __restrict__ x,
                                           const float* __restrict__ emb,
                                           float* __restrict__ out) {
    __shared__ float lds[2 * TABROWS];               // 128 KiB, one level (AoS float2)
    const int tid = threadIdx.x;
    const int b = blockIdx.x * BLK + tid;

    const float pc0 = x[3*b + 0];
    const float pc1 = x[3*b + 1];
    const float pc2 = x[3*b + 2];

    float acc[2 * NLG];                              // 16 fp32, static-indexed

    // prelude: async-stage level LBASE (full 128 KiB slice, no guards)
    {
        const char* g = (const char*)emb + (size_t)LBASE * LVLBYTES;
        char* l = (char*)lds;
#pragma unroll
        for (int base = 0; base < LVLBYTES; base += BLK * 16) {
            int o = base + tid * 16;
            __builtin_amdgcn_global_load_lds((gv_t*)(g + o), (lv_t*)(l + o), 16, 0, 0);
        }
    }

#pragma unroll
    for (int i = 0; i < NLG; ++i) {
        const int lvl = LBASE + i;
        // barrier 1: __syncthreads drains vmcnt -> staging of `lvl` landed
        // for all waves before anyone gathers.
        __syncthreads();

        const int r = RES_[lvl];
        const bool hashing = (lvl >= 3);
        const float rh = 0.5f * (float)r;            // exact (pow2 * small int)

        uint32_t t[3][2];
        float w[3][2];
        const float pc[3] = {pc0, pc1, pc2};
        const uint32_t PRIME[3]  = {1u, 2654435761u, 805459861u};
        const uint32_t STRIDE[3] = {1u, (uint32_t)r, (uint32_t)(r * r)};

#pragma unroll
        for (int d = 0; d < 3; ++d) {
            // ((x+1)*res)*0.5 - 0.5 == (x+1)*(res*0.5) - 0.5 (pow2 scaling exact)
            float xs = (pc[d] + 1.0f) * rh - 0.5f;
            float fl = floorf(xs);
            float xf = xs - fl;
            int xi = (int)fl;
            bool v0 = (xi >= 0) && (xi < r);
            bool v1 = (xi >= -1) && (xi < r - 1);
            w[d][0] = v0 ? (1.0f - xf) : 0.0f;       // validity folded into weights
            w[d][1] = v1 ? xf : 0.0f;
            if (hashing) {
                t[d][0] = (uint32_t)xi * PRIME[d];   // uint32 wrap == ref semantics
                t[d][1] = t[d][0] + PRIME[d];        // (xi+1)*P mod 2^32
            } else {
                // zeroed invalid contributions keep idx in [0, r^3) with no mod
                t[d][0] = v0 ? (uint32_t)xi * STRIDE[d] : 0u;
                t[d][1] = v1 ? (uint32_t)(xi + 1) * STRIDE[d] : 0u;
            }
        }

        const float2* buf = (const float2*)lds;
        float a0 = 0.0f, a1 = 0.0f;
#pragma unroll
        for (int o0 = 0; o0 < 2; ++o0) {
#pragma unroll
            for (int o1 = 0; o1 < 2; ++o1) {
                uint32_t q01 = hashing ? (t[0][o0] ^ t[1][o1]) : (t[0][o0] + t[1][o1]);
                float w01 = w[0][o0] * w[1][o1];
#pragma unroll
                for (int o2 = 0; o2 < 2; ++o2) {
                    uint32_t idx = hashing ? ((q01 ^ t[2][o2]) & 16383u)
                                           : (q01 + t[2][o2]);
                    float wc = w01 * w[2][o2];
                    float2 e = buf[idx];             // ds_read_b64: fp32x2 entry
                    a0 = fmaf(wc, e.x, a0);
                    a1 = fmaf(wc, e.y, a1);
                }
            }
        }
        acc[2 * i + 0] = a0;
        acc[2 * i + 1] = a1;

        if (i + 1 < NLG) {
            // barrier 2: every wave finished gathering `lvl` before the stage
            // of `lvl+1` starts overwriting the single buffer.
            __syncthreads();
            const char* g = (const char*)emb + (size_t)(lvl + 1) * LVLBYTES;
            char* l = (char*)lds;
#pragma unroll
            for (int base = 0; base < LVLBYTES; base += BLK * 16) {
                int o = base + tid * 16;
                __builtin_amdgcn_global_load_lds((gv_t*)(g + o), (lv_t*)(l + o), 16, 0, 0);
            }
        }
    }

    // epilogue: this group's 64 B half-line, 4 x float4 (exact fp32, no unscale)
    float4* o4 = (float4*)(out + (size_t)b * (2 * NLVL) + 2 * LBASE);
#pragma unroll
    for (int k = 0; k < (2 * NLG) / 4; ++k)
        o4[k] = make_float4(acc[4*k + 0], acc[4*k + 1],
                            acc[4*k + 2], acc[4*k + 3]);
}

extern "C" void kernel_launch(void* const* d_in, const int* in_sizes, int n_in,
                              void* d_out, int out_size, void* d_ws, size_t ws_size,
                              hipStream_t stream) {
    const float* x   = (const float*)d_in[0];   // (B, 3) fp32
    const float* emb = (const float*)d_in[1];   // (16, 16384, 2) fp32
    float* out = (float*)d_out;                 // (B, 16, 2) fp32
    (void)d_ws; (void)ws_size;                  // workspace intentionally unused

    enc<0><<<NBLK, BLK, 0, stream>>>(x, emb, out);
    enc<8><<<NBLK, BLK, 0, stream>>>(x, emb, out);
}

// Round 7
// 270.280 us; speedup vs baseline: 1.1105x; 1.1105x over previous
//
#include <hip/hip_runtime.h>
#include <hip/hip_fp16.h>
#include <stdint.h>
#include <stddef.h>

#define NLVL 16
#define TABROWS 16384
#define BLK 1024
#define NPP 4                         // points per thread in gather
#define CHUNK (BLK * NPP)             // 4096 points per block
#define NCHUNK (1048576 / CHUNK)      // 256
#define GGRID (NCHUNK * NLVL)         // 4096 blocks, lvl = bid & 15
#define NPTS 1048576
#define TSCALE 8192.0f                // 2^13: keeps |emb|*scale in fp16-normal range
#define TINV   (1.0f / 8192.0f)
#define MIDOFF (1u << 21)             // intermediate at d_ws + 2 MiB (tables: 1 MiB)

constexpr int RES_[NLVL]  = {16,20,25,32,40,50,64,80,101,128,161,203,256,322,406,512};
// staged bytes per level (4 B/entry fp16x2), rounded up to 16
constexpr int NBYTES_[NLVL] = {16384,32000,62512,65536,65536,65536,65536,65536,
                               65536,65536,65536,65536,65536,65536,65536,65536};

typedef __attribute__((address_space(1))) void gv_t;
typedef __attribute__((address_space(3))) void lv_t;

// ---- kernel 1: convert fp32 tables -> scaled fp16x2 in workspace (1 MiB) ----
__global__ __launch_bounds__(256) void cvt_tab(const float* __restrict__ src,
                                               uint32_t* __restrict__ dst) {
    int i = blockIdx.x * 256 + threadIdx.x;          // 131072 threads, 4 floats each
    float4 v = ((const float4*)src)[i];
    __half2 a = __floats2half2_rn(v.x * TSCALE, v.y * TSCALE);
    __half2 b = __floats2half2_rn(v.z * TSCALE, v.w * TSCALE);
    uint2 o;
    o.x = *(uint32_t*)&a;
    o.y = *(uint32_t*)&b;
    ((uint2*)dst)[i] = o;
}

// one level, one point: trilinear 8-corner gather-blend from LDS table
template<bool HASH>
__device__ __forceinline__ void level_point(const uint32_t* __restrict__ buf,
                                            float px, float py, float pz,
                                            int r, float rh,
                                            float& a0, float& a1) {
    uint32_t t[3][2];
    float w[3][2];
    const float pcp[3] = {px, py, pz};
    const uint32_t PRIME[3]  = {1u, 2654435761u, 805459861u};
    const uint32_t STRIDE[3] = {1u, (uint32_t)r, (uint32_t)(r * r)};
#pragma unroll
    for (int d = 0; d < 3; ++d) {
        // ((x+1)*res)*0.5 - 0.5 == (x+1)*(res*0.5) - 0.5 (pow2 scaling exact)
        float xs = (pcp[d] + 1.0f) * rh - 0.5f;
        float fl = floorf(xs);
        float xf = xs - fl;
        int xi = (int)fl;
        bool v0 = (xi >= 0) && (xi < r);
        bool v1 = (xi >= -1) && (xi < r - 1);
        w[d][0] = v0 ? (1.0f - xf) : 0.0f;           // validity folded into weights
        w[d][1] = v1 ? xf : 0.0f;
        if (HASH) {
            t[d][0] = (uint32_t)xi * PRIME[d];       // uint32 wrap == ref semantics
            t[d][1] = t[d][0] + PRIME[d];            // (xi+1)*P mod 2^32
        } else {
            // zeroed invalid contributions keep idx in [0, r^3) with no mod
            t[d][0] = v0 ? (uint32_t)xi * STRIDE[d] : 0u;
            t[d][1] = v1 ? (uint32_t)(xi + 1) * STRIDE[d] : 0u;
        }
    }
    a0 = 0.0f; a1 = 0.0f;
#pragma unroll
    for (int o0 = 0; o0 < 2; ++o0) {
#pragma unroll
        for (int o1 = 0; o1 < 2; ++o1) {
            uint32_t q01 = HASH ? (t[0][o0] ^ t[1][o1]) : (t[0][o0] + t[1][o1]);
            float w01 = w[0][o0] * w[1][o1];
#pragma unroll
            for (int o2 = 0; o2 < 2; ++o2) {
                uint32_t idx = HASH ? ((q01 ^ t[2][o2]) & 16383u)
                                    : (q01 + t[2][o2]);
                float wc = w01 * w[2][o2];
                uint32_t pk = buf[idx];              // ds_read_b32: fp16x2 entry
                __half2 h = *(__half2*)&pk;
                a0 = fmaf(wc, __low2float(h), a0);
                a1 = fmaf(wc, __high2float(h), a1);
            }
        }
    }
}

// ---- kernel 2 (LEVEL-MAJOR): one block = one level x 4096 points.
//      One 64 KiB stage + ONE barrier per block, then a long uninterrupted
//      gather stream (4x the per-phase work of the point-major structure,
//      1/8 the barriers): per-CU phase count drops 64 -> 16. Output goes to a
//      level-major fp32 intermediate in the workspace (coalesced float2
//      stores); the workspace poison fill is unconditional (round 6), so
//      using d_ws is free. lvl = bid & 15: the 16 blocks of a point-chunk are
//      dispatch-adjacent -> x chunk (48 KiB) is L2-hot, and all 16 fp16
//      tables (1 MiB) stay hot in every XCD L2. VGPR stays ~55 (<= 64 wall:
//      per-point temps die between the serial k iterations). ----
__global__ __launch_bounds__(BLK) void gather(const float* __restrict__ x,
                                              const uint32_t* __restrict__ tab,
                                              float2* __restrict__ mid) {
    __shared__ uint32_t lds[TABROWS];                // 64 KiB, this block's level
    const int tid = threadIdx.x;
    const int lvl = blockIdx.x & (NLVL - 1);
    const int chunk = blockIdx.x >> 4;
    const int p0 = chunk * CHUNK + tid;              // points p0 + k*BLK

    // stage this level's fp16x2 table slice (<= 64 KiB)
    {
        const int nb = NBYTES_[lvl];
        const char* g = (const char*)tab + (size_t)lvl * TABROWS * 4;
        char* l = (char*)lds;
#pragma unroll
        for (int base = 0; base < TABROWS * 4; base += BLK * 16) {
            int o = base + tid * 16;
            if (o < nb)
                __builtin_amdgcn_global_load_lds((gv_t*)(g + o), (lv_t*)(l + o), 16, 0, 0);
        }
    }
    // single barrier: drains this wave's global_load_lds, then all staged.
    __syncthreads();

    const int r = RES_[lvl];                         // wave-uniform scalar
    const float rh = 0.5f * (float)r;                // exact (pow2 * small int)
    float2* dst = mid + (size_t)lvl * NPTS;

    if (lvl >= 3) {                                  // uniform branch: hash path
#pragma unroll
        for (int k = 0; k < NPP; ++k) {
            const int p = p0 + k * BLK;
            float a0, a1;
            level_point<true>(lds, x[3*p], x[3*p + 1], x[3*p + 2], r, rh, a0, a1);
            dst[p] = make_float2(a0 * TINV, a1 * TINV);   // coalesced 8 B store
        }
    } else {                                         // dense ravel path (lvl 0..2)
#pragma unroll
        for (int k = 0; k < NPP; ++k) {
            const int p = p0 + k * BLK;
            float a0, a1;
            level_point<false>(lds, x[3*p], x[3*p + 1], x[3*p + 2], r, rh, a0, a1);
            dst[p] = make_float2(a0 * TINV, a1 * TINV);
        }
    }
}

// ---- kernel 3: transpose level-major (16, 1M, 2) -> point-major (1M, 16, 2).
//      Reads: per level, lanes hit consecutive points -> coalesced 512 B/wave.
//      Writes: 128 B contiguous per thread (8 x float4). Intermediate is
//      134 MB < 256 MB L3, so reads mostly L3-hit. ----
__global__ __launch_bounds__(256) void xpose(const float2* __restrict__ mid,
                                             float* __restrict__ out) {
    const int p = blockIdx.x * 256 + threadIdx.x;
    float2 v[NLVL];
#pragma unroll
    for (int l = 0; l < NLVL; ++l)
        v[l] = mid[(size_t)l * NPTS + p];            // 16 independent loads in flight
    float4* o4 = (float4*)(out + (size_t)p * (2 * NLVL));
#pragma unroll
    for (int k = 0; k < NLVL / 2; ++k)
        o4[k] = make_float4(v[2*k].x, v[2*k].y, v[2*k + 1].x, v[2*k + 1].y);
}

extern "C" void kernel_launch(void* const* d_in, const int* in_sizes, int n_in,
                              void* d_out, int out_size, void* d_ws, size_t ws_size,
                              hipStream_t stream) {
    const float* x   = (const float*)d_in[0];   // (B, 3) fp32
    const float* emb = (const float*)d_in[1];   // (16, 16384, 2) fp32
    float* out = (float*)d_out;                 // (B, 16, 2) fp32
    uint32_t* tab = (uint32_t*)d_ws;            // fp16x2 tables: 1 MiB at offset 0
    float2* mid = (float2*)((char*)d_ws + MIDOFF);   // (16, 1M) float2: 128 MiB

    cvt_tab<<<512, 256, 0, stream>>>(emb, tab);
    gather<<<GGRID, BLK, 0, stream>>>(x, tab, mid);
    xpose<<<NPTS / 256, 256, 0, stream>>>(mid, out);
}

// Round 9
// 222.630 us; speedup vs baseline: 1.3481x; 1.2140x over previous
//
#include <hip/hip_runtime.h>
#include <hip/hip_fp16.h>
#include <stdint.h>
#include <stddef.h>

#define NLVL 16
#define TABROWS 16384
#define BLK 1024
#define NPP 4                         // points per thread in gather
#define CHUNK (BLK * NPP)             // 4096 points per block
#define NCHUNK (1048576 / CHUNK)      // 256
#define GGRID (NCHUNK * NLVL)         // 4096 blocks, lvl = bid & 15
#define NPTS 1048576
#define TSCALE 8192.0f                // 2^13: keeps |emb|*scale in fp16-normal range
#define TINV   (1.0f / 8192.0f)
#define MIDOFF (1u << 21)             // intermediate at d_ws + 2 MiB (tables: 1 MiB)

constexpr int RES_[NLVL]  = {16,20,25,32,40,50,64,80,101,128,161,203,256,322,406,512};
// staged bytes per level (4 B/entry fp16x2), rounded up to 16
constexpr int NBYTES_[NLVL] = {16384,32000,62512,65536,65536,65536,65536,65536,
                               65536,65536,65536,65536,65536,65536,65536,65536};

typedef __attribute__((address_space(1))) void gv_t;
typedef __attribute__((address_space(3))) void lv_t;

// ---- kernel 1: convert fp32 tables -> scaled fp16x2 in workspace (1 MiB) ----
__global__ __launch_bounds__(256) void cvt_tab(const float* __restrict__ src,
                                               uint32_t* __restrict__ dst) {
    int i = blockIdx.x * 256 + threadIdx.x;          // 131072 threads, 4 floats each
    float4 v = ((const float4*)src)[i];
    __half2 a = __floats2half2_rn(v.x * TSCALE, v.y * TSCALE);
    __half2 b = __floats2half2_rn(v.z * TSCALE, v.w * TSCALE);
    uint2 o;
    o.x = *(uint32_t*)&a;
    o.y = *(uint32_t*)&b;
    ((uint2*)dst)[i] = o;
}

// one level, one point: trilinear 8-corner gather-blend from LDS table
template<bool HASH>
__device__ __forceinline__ void level_point(const uint32_t* __restrict__ buf,
                                            float px, float py, float pz,
                                            int r, float rh,
                                            float& a0, float& a1) {
    uint32_t t[3][2];
    float w[3][2];
    const float pcp[3] = {px, py, pz};
    const uint32_t PRIME[3]  = {1u, 2654435761u, 805459861u};
    const uint32_t STRIDE[3] = {1u, (uint32_t)r, (uint32_t)(r * r)};
#pragma unroll
    for (int d = 0; d < 3; ++d) {
        // ((x+1)*res)*0.5 - 0.5 == (x+1)*(res*0.5) - 0.5 (pow2 scaling exact)
        float xs = (pcp[d] + 1.0f) * rh - 0.5f;
        float fl = floorf(xs);
        float xf = xs - fl;
        int xi = (int)fl;
        bool v0 = (xi >= 0) && (xi < r);
        bool v1 = (xi >= -1) && (xi < r - 1);
        w[d][0] = v0 ? (1.0f - xf) : 0.0f;           // validity folded into weights
        w[d][1] = v1 ? xf : 0.0f;
        if (HASH) {
            t[d][0] = (uint32_t)xi * PRIME[d];       // uint32 wrap == ref semantics
            t[d][1] = t[d][0] + PRIME[d];            // (xi+1)*P mod 2^32
        } else {
            // zeroed invalid contributions keep idx in [0, r^3) with no mod
            t[d][0] = v0 ? (uint32_t)xi * STRIDE[d] : 0u;
            t[d][1] = v1 ? (uint32_t)(xi + 1) * STRIDE[d] : 0u;
        }
    }
    a0 = 0.0f; a1 = 0.0f;
#pragma unroll
    for (int o0 = 0; o0 < 2; ++o0) {
#pragma unroll
        for (int o1 = 0; o1 < 2; ++o1) {
            uint32_t q01 = HASH ? (t[0][o0] ^ t[1][o1]) : (t[0][o0] + t[1][o1]);
            float w01 = w[0][o0] * w[1][o1];
#pragma unroll
            for (int o2 = 0; o2 < 2; ++o2) {
                uint32_t idx = HASH ? ((q01 ^ t[2][o2]) & 16383u)
                                    : (q01 + t[2][o2]);
                float wc = w01 * w[2][o2];
                uint32_t pk = buf[idx];              // ds_read_b32: fp16x2 entry
                __half2 h = *(__half2*)&pk;
                a0 = fmaf(wc, __low2float(h), a0);
                a1 = fmaf(wc, __high2float(h), a1);
            }
        }
    }
}

// ---- kernel 2 (LEVEL-MAJOR): one block = one level x 4096 points.
//      One 64 KiB stage + ONE barrier per block, then a long uninterrupted
//      gather stream. Output goes to a level-major SCALED-FP16x2 intermediate
//      in the workspace (half of round 7's fp32 mid: 64 MiB instead of 128 --
//      halves gather store traffic, xpose read traffic, and the dirty-L3
//      footprint that slowed the unconditional poison fill 83->110 us).
//      Quantization adds ~3e-8 on top of the 4.77e-7 harness comparison
//      floor (absmax was bit-identical across fp16 and pure-fp32 rounds).
//      VGPR ~55 (<= 64 wall at BLK=1024), no spill. ----
__global__ __launch_bounds__(BLK) void gather(const float* __restrict__ x,
                                              const uint32_t* __restrict__ tab,
                                              uint32_t* __restrict__ mid) {
    __shared__ uint32_t lds[TABROWS];                // 64 KiB, this block's level
    const int tid = threadIdx.x;
    const int lvl = blockIdx.x & (NLVL - 1);
    const int chunk = blockIdx.x >> 4;
    const int p0 = chunk * CHUNK + tid;              // points p0 + k*BLK

    // stage this level's fp16x2 table slice (<= 64 KiB)
    {
        const int nb = NBYTES_[lvl];
        const char* g = (const char*)tab + (size_t)lvl * TABROWS * 4;
        char* l = (char*)lds;
#pragma unroll
        for (int base = 0; base < TABROWS * 4; base += BLK * 16) {
            int o = base + tid * 16;
            if (o < nb)
                __builtin_amdgcn_global_load_lds((gv_t*)(g + o), (lv_t*)(l + o), 16, 0, 0);
        }
    }
    // single barrier: drains this wave's global_load_lds, then all staged.
    __syncthreads();

    const int r = RES_[lvl];                         // wave-uniform scalar
    const float rh = 0.5f * (float)r;                // exact (pow2 * small int)
    uint32_t* dst = mid + (size_t)lvl * NPTS;

    if (lvl >= 3) {                                  // uniform branch: hash path
#pragma unroll
        for (int k = 0; k < NPP; ++k) {
            const int p = p0 + k * BLK;
            float a0, a1;
            level_point<true>(lds, x[3*p], x[3*p + 1], x[3*p + 2], r, rh, a0, a1);
            __half2 h = __floats2half2_rn(a0, a1);   // stay in scaled domain
            dst[p] = *(uint32_t*)&h;                 // coalesced 4 B store
        }
    } else {                                         // dense ravel path (lvl 0..2)
#pragma unroll
        for (int k = 0; k < NPP; ++k) {
            const int p = p0 + k * BLK;
            float a0, a1;
            level_point<false>(lds, x[3*p], x[3*p + 1], x[3*p + 2], r, rh, a0, a1);
            __half2 h = __floats2half2_rn(a0, a1);
            dst[p] = *(uint32_t*)&h;
        }
    }
}

// ---- kernel 3: transpose level-major (16, 1M) fp16x2 -> point-major
//      (1M, 16, 2) fp32 with the 2^-13 unscale. Reads: consecutive lanes hit
//      consecutive points -> 256 B/wave/level, 64 MiB total (mostly L3-hot,
//      just written by gather). Writes: 128 B contiguous per thread. ----
__global__ __launch_bounds__(256) void xpose(const uint32_t* __restrict__ mid,
                                             float* __restrict__ out) {
    const int p = blockIdx.x * 256 + threadIdx.x;
    uint32_t v[NLVL];
#pragma unroll
    for (int l = 0; l < NLVL; ++l)
        v[l] = mid[(size_t)l * NPTS + p];            // 16 independent loads in flight
    float4* o4 = (float4*)(out + (size_t)p * (2 * NLVL));
#pragma unroll
    for (int k = 0; k < NLVL / 2; ++k) {
        __half2 h0 = *(__half2*)&v[2*k + 0];
        __half2 h1 = *(__half2*)&v[2*k + 1];
        o4[k] = make_float4(__low2float(h0) * TINV, __high2float(h0) * TINV,
                            __low2float(h1) * TINV, __high2float(h1) * TINV);
    }
}

extern "C" void kernel_launch(void* const* d_in, const int* in_sizes, int n_in,
                              void* d_out, int out_size, void* d_ws, size_t ws_size,
                              hipStream_t stream) {
    const float* x   = (const float*)d_in[0];   // (B, 3) fp32
    const float* emb = (const float*)d_in[1];   // (16, 16384, 2) fp32
    float* out = (float*)d_out;                 // (B, 16, 2) fp32
    uint32_t* tab = (uint32_t*)d_ws;            // fp16x2 tables: 1 MiB at offset 0
    uint32_t* mid = (uint32_t*)((char*)d_ws + MIDOFF); // (16, 1M) fp16x2: 64 MiB

    cvt_tab<<<512, 256, 0, stream>>>(emb, tab);
    gather<<<GGRID, BLK, 0, stream>>>(x, tab, mid);
    xpose<<<NPTS / 256, 256, 0, stream>>>(mid, out);
}

// Round 10
// 217.024 us; speedup vs baseline: 1.3830x; 1.0258x over previous
//
#include <hip/hip_runtime.h>
#include <hip/hip_fp16.h>
#include <stdint.h>
#include <stddef.h>

#define NLVL 16
#define TABROWS 16384
#define BLK 1024
#define NPG 4                         // consecutive points per thread per group
#define NGRP 2                        // groups per block
#define CHUNK (BLK * NPG * NGRP)      // 8192 points per block
#define NCHUNK (1048576 / CHUNK)      // 128
#define GGRID (NCHUNK * NLVL)         // 2048 blocks, lvl = bid & 15
#define NPTS 1048576
#define TSCALE 8192.0f                // 2^13: keeps |emb|*scale in fp16-normal range
#define TINV   (1.0f / 8192.0f)
#define MIDOFF (1u << 21)             // intermediate at d_ws + 2 MiB (tables: 1 MiB)

constexpr int RES_[NLVL]  = {16,20,25,32,40,50,64,80,101,128,161,203,256,322,406,512};
// staged bytes per level (4 B/entry fp16x2), rounded up to 16
constexpr int NBYTES_[NLVL] = {16384,32000,62512,65536,65536,65536,65536,65536,
                               65536,65536,65536,65536,65536,65536,65536,65536};

typedef __attribute__((address_space(1))) void gv_t;
typedef __attribute__((address_space(3))) void lv_t;

// ---- kernel 1: convert fp32 tables -> scaled fp16x2 in workspace (1 MiB) ----
__global__ __launch_bounds__(256) void cvt_tab(const float* __restrict__ src,
                                               uint32_t* __restrict__ dst) {
    int i = blockIdx.x * 256 + threadIdx.x;          // 131072 threads, 4 floats each
    float4 v = ((const float4*)src)[i];
    __half2 a = __floats2half2_rn(v.x * TSCALE, v.y * TSCALE);
    __half2 b = __floats2half2_rn(v.z * TSCALE, v.w * TSCALE);
    uint2 o;
    o.x = *(uint32_t*)&a;
    o.y = *(uint32_t*)&b;
    ((uint2*)dst)[i] = o;
}

// one level, one point: trilinear 8-corner gather-blend from LDS table
template<bool HASH>
__device__ __forceinline__ void level_point(const uint32_t* __restrict__ buf,
                                            float px, float py, float pz,
                                            int r, float rh,
                                            float& a0, float& a1) {
    uint32_t t[3][2];
    float w[3][2];
    const float pcp[3] = {px, py, pz};
    const uint32_t PRIME[3]  = {1u, 2654435761u, 805459861u};
    const uint32_t STRIDE[3] = {1u, (uint32_t)r, (uint32_t)(r * r)};
#pragma unroll
    for (int d = 0; d < 3; ++d) {
        // ((x+1)*res)*0.5 - 0.5 == (x+1)*(res*0.5) - 0.5 (pow2 scaling exact)
        float xs = (pcp[d] + 1.0f) * rh - 0.5f;
        float fl = floorf(xs);
        float xf = xs - fl;
        int xi = (int)fl;
        bool v0 = (xi >= 0) && (xi < r);
        bool v1 = (xi >= -1) && (xi < r - 1);
        w[d][0] = v0 ? (1.0f - xf) : 0.0f;           // validity folded into weights
        w[d][1] = v1 ? xf : 0.0f;
        if (HASH) {
            t[d][0] = (uint32_t)xi * PRIME[d];       // uint32 wrap == ref semantics
            t[d][1] = t[d][0] + PRIME[d];            // (xi+1)*P mod 2^32
        } else {
            // zeroed invalid contributions keep idx in [0, r^3) with no mod
            t[d][0] = v0 ? (uint32_t)xi * STRIDE[d] : 0u;
            t[d][1] = v1 ? (uint32_t)(xi + 1) * STRIDE[d] : 0u;
        }
    }
    a0 = 0.0f; a1 = 0.0f;
#pragma unroll
    for (int o0 = 0; o0 < 2; ++o0) {
#pragma unroll
        for (int o1 = 0; o1 < 2; ++o1) {
            uint32_t q01 = HASH ? (t[0][o0] ^ t[1][o1]) : (t[0][o0] + t[1][o1]);
            float w01 = w[0][o0] * w[1][o1];
#pragma unroll
            for (int o2 = 0; o2 < 2; ++o2) {
                uint32_t idx = HASH ? ((q01 ^ t[2][o2]) & 16383u)
                                    : (q01 + t[2][o2]);
                float wc = w01 * w[2][o2];
                uint32_t pk = buf[idx];              // ds_read_b32: fp16x2 entry
                __half2 h = *(__half2*)&pk;
                a0 = fmaf(wc, __low2float(h), a0);
                a1 = fmaf(wc, __high2float(h), a1);
            }
        }
    }
}

// 4 consecutive points: 3 aligned float4 x-loads, 1 uint4 mid-store
template<bool HASH>
__device__ __forceinline__ void gather4(const uint32_t* __restrict__ buf,
                                        const float* __restrict__ x,
                                        uint32_t* __restrict__ dst,
                                        int q, int r, float rh) {
    const float4* xv = (const float4*)(x + 3 * (size_t)q);   // 48 B, 16-B aligned
    float4 v0 = xv[0], v1 = xv[1], v2 = xv[2];
    float px[4] = {v0.x, v0.w, v1.z, v2.y};
    float py[4] = {v0.y, v1.x, v1.w, v2.z};
    float pz[4] = {v0.z, v1.y, v2.x, v2.w};
    uint4 res;
    uint32_t* rp = (uint32_t*)&res;
#pragma unroll
    for (int k = 0; k < NPG; ++k) {
        float a0, a1;
        level_point<HASH>(buf, px[k], py[k], pz[k], r, rh, a0, a1);
        __half2 h = __floats2half2_rn(a0, a1);       // stay in scaled domain
        rp[k] = *(uint32_t*)&h;
    }
    *(uint4*)(dst + q) = res;                        // 16 B coalesced store
}

// ---- kernel 2 (LEVEL-MAJOR): one block = one level x 8192 points.
//      One 64 KiB stage + ONE barrier per block, then a long uninterrupted
//      gather stream. vs round 9: blocks halved (2048) -> per-CU stage+barrier
//      phases halve 16->8; thread->point mapping now 4 CONSECUTIVE points
//      (x2 groups), turning 12 scalar x-loads into 3 float4 and 4 scalar
//      mid-stores into 1 uint4. Temps die between the two groups, holding
//      VGPR at the 4-point level (<= 64 wall at BLK=1024). Output: scaled
//      fp16x2 level-major mid (64 MiB) in the already-poisoned workspace. ----
__global__ __launch_bounds__(BLK) void gather(const float* __restrict__ x,
                                              const uint32_t* __restrict__ tab,
                                              uint32_t* __restrict__ mid) {
    __shared__ uint32_t lds[TABROWS];                // 64 KiB, this block's level
    const int tid = threadIdx.x;
    const int lvl = blockIdx.x & (NLVL - 1);
    const int chunk = blockIdx.x >> 4;

    // stage this level's fp16x2 table slice (<= 64 KiB)
    {
        const int nb = NBYTES_[lvl];
        const char* g = (const char*)tab + (size_t)lvl * TABROWS * 4;
        char* l = (char*)lds;
#pragma unroll
        for (int base = 0; base < TABROWS * 4; base += BLK * 16) {
            int o = base + tid * 16;
            if (o < nb)
                __builtin_amdgcn_global_load_lds((gv_t*)(g + o), (lv_t*)(l + o), 16, 0, 0);
        }
    }
    // single barrier: drains this wave's global_load_lds, then all staged.
    __syncthreads();

    const int r = RES_[lvl];                         // wave-uniform scalar
    const float rh = 0.5f * (float)r;                // exact (pow2 * small int)
    uint32_t* dst = mid + (size_t)lvl * NPTS;
    const int base = chunk * CHUNK;

    if (lvl >= 3) {                                  // uniform branch: hash path
#pragma unroll
        for (int g = 0; g < NGRP; ++g)
            gather4<true>(lds, x, dst, base + g * (BLK * NPG) + tid * NPG, r, rh);
    } else {                                         // dense ravel path (lvl 0..2)
#pragma unroll
        for (int g = 0; g < NGRP; ++g)
            gather4<false>(lds, x, dst, base + g * (BLK * NPG) + tid * NPG, r, rh);
    }
}

// ---- kernel 3: transpose level-major (16, 1M) fp16x2 -> point-major
//      (1M, 16, 2) fp32 with the 2^-13 unscale. Reads: consecutive lanes hit
//      consecutive points -> 256 B/wave/level, 64 MiB total (mostly L3-hot,
//      just written by gather). Writes: 128 B contiguous per thread. ----
__global__ __launch_bounds__(256) void xpose(const uint32_t* __restrict__ mid,
                                             float* __restrict__ out) {
    const int p = blockIdx.x * 256 + threadIdx.x;
    uint32_t v[NLVL];
#pragma unroll
    for (int l = 0; l < NLVL; ++l)
        v[l] = mid[(size_t)l * NPTS + p];            // 16 independent loads in flight
    float4* o4 = (float4*)(out + (size_t)p * (2 * NLVL));
#pragma unroll
    for (int k = 0; k < NLVL / 2; ++k) {
        __half2 h0 = *(__half2*)&v[2*k + 0];
        __half2 h1 = *(__half2*)&v[2*k + 1];
        o4[k] = make_float4(__low2float(h0) * TINV, __high2float(h0) * TINV,
                            __low2float(h1) * TINV, __high2float(h1) * TINV);
    }
}

extern "C" void kernel_launch(void* const* d_in, const int* in_sizes, int n_in,
                              void* d_out, int out_size, void* d_ws, size_t ws_size,
                              hipStream_t stream) {
    const float* x   = (const float*)d_in[0];   // (B, 3) fp32
    const float* emb = (const float*)d_in[1];   // (16, 16384, 2) fp32
    float* out = (float*)d_out;                 // (B, 16, 2) fp32
    uint32_t* tab = (uint32_t*)d_ws;            // fp16x2 tables: 1 MiB at offset 0
    uint32_t* mid = (uint32_t*)((char*)d_ws + MIDOFF); // (16, 1M) fp16x2: 64 MiB

    cvt_tab<<<512, 256, 0, stream>>>(emb, tab);
    gather<<<GGRID, BLK, 0, stream>>>(x, tab, mid);
    xpose<<<NPTS / 256, 256, 0, stream>>>(mid, out);
}